// Round 3
// baseline (33.147 us; speedup 1.0000x reference)
//
#include <hip/hip_runtime.h>

// Problem constants (from reference)
#define N_IDEAS 5
#define N_EXPERTS 10
#define OUT_DIM 784          // 28*28
#define CHUNKS 196           // OUT_DIM / 4 (float4 chunks per sample)
#define BATCH 32768
#define SPB 64               // samples per block
#define BLOCK 256            // threads; 196 active in compute (one per chunk)

// Each thread owns ONE float4 output chunk and register-caches W for ALL 10
// experts at that chunk (10 x 5 float4 = 200 VGPRs). Expert id is uniform
// per sample across the block -> uniform switch, compile-time register
// indices. Inner loop: 5 broadcast LDS reads + 1 b128 + 20 FMA + 1 store of
// a fully contiguous 3136B sample row. Store-BW bound.
__global__ __launch_bounds__(BLOCK) void moe_expert_reg_kernel(
    const float* __restrict__ x,      // [B, 5]
    const int* __restrict__ labels,   // [B]
    const float* __restrict__ W,      // [E, 784, 5]
    const float* __restrict__ b,      // [E, 784]
    float4* __restrict__ out)         // [B*196]
{
    __shared__ float4 bl[N_EXPERTS * CHUNKS];   // whole bias, 31.4 KB
    __shared__ float  xl[SPB * N_IDEAS];        // 1.25 KB
    __shared__ int    ll[SPB];                  // 256 B

    const int tid = threadIdx.x;
    const int sg  = blockIdx.x;                 // sample group [sg*64, +64)

    // ---- stage bias (entire array), x slab, labels
    const float4* bg = (const float4*)b;
    for (int i = tid; i < N_EXPERTS * CHUNKS; i += BLOCK)   // 1960 f4
        bl[i] = bg[i];
    const float4* xg = (const float4*)x;
    float4* xl4 = (float4*)xl;
    if (tid < (SPB * N_IDEAS) / 4)                          // 80 f4
        xl4[tid] = xg[sg * ((SPB * N_IDEAS) / 4) + tid];
    const int4* lg = (const int4*)labels;
    if (tid < SPB / 4)                                      // 16 i4
        ((int4*)ll)[tid] = lg[sg * (SPB / 4) + tid];

    // ---- register-cache W[e][own chunk] for all experts: 50 float4 loads
    const int c = tid;                          // owned chunk, active if <196
    float4 w[N_EXPERTS][5];
    if (c < CHUNKS) {
        const float4* Wg = (const float4*)W;    // W row-stride: 980 f4/expert
#pragma unroll
        for (int e = 0; e < N_EXPERTS; ++e)
#pragma unroll
            for (int r = 0; r < 5; ++r)
                w[e][r] = Wg[e * 980 + c * 5 + r];
    }
    __syncthreads();

    const size_t base = (size_t)sg * SPB * CHUNKS + c;
    for (int s = 0; s < SPB; ++s) {
        const int e = __builtin_amdgcn_readfirstlane(ll[s]);   // block-uniform
        const float* xp = &xl[s * N_IDEAS];
        const float x0 = xp[0], x1 = xp[1], x2 = xp[2], x3 = xp[3], x4 = xp[4];
        if (c < CHUNKS) {
            const float4 bb = bl[e * CHUNKS + c];   // lane-stride 16B: conflict-free
            float4 r;
            switch (e) {
#define DO(E) case E: \
    r.x = bb.x + w[E][0].x*x0 + w[E][0].y*x1 + w[E][0].z*x2 + w[E][0].w*x3 + w[E][1].x*x4; \
    r.y = bb.y + w[E][1].y*x0 + w[E][1].z*x1 + w[E][1].w*x2 + w[E][2].x*x3 + w[E][2].y*x4; \
    r.z = bb.z + w[E][2].z*x0 + w[E][2].w*x1 + w[E][3].x*x2 + w[E][3].y*x3 + w[E][3].z*x4; \
    r.w = bb.w + w[E][3].w*x0 + w[E][4].x*x1 + w[E][4].y*x2 + w[E][4].z*x3 + w[E][4].w*x4; \
    break;
                DO(0) DO(1) DO(2) DO(3) DO(4) DO(5) DO(6) DO(7) DO(8) DO(9)
#undef DO
            }
            out[base + (size_t)s * CHUNKS] = r;     // 196 lanes: 3136B contiguous
        }
    }
}

extern "C" void kernel_launch(void* const* d_in, const int* in_sizes, int n_in,
                              void* d_out, int out_size, void* d_ws, size_t ws_size,
                              hipStream_t stream) {
    const float* x      = (const float*)d_in[0];
    const int*   labels = (const int*)d_in[1];
    const float* W      = (const float*)d_in[2];
    const float* b      = (const float*)d_in[3];
    float4* out = (float4*)d_out;

    const int grid = BATCH / SPB;               // 512 blocks, ~2/CU
    moe_expert_reg_kernel<<<grid, BLOCK, 0, stream>>>(x, labels, W, b, out);
}